// Round 6
// baseline (63.031 us; speedup 1.0000x reference)
//
#include <hip/hip_runtime.h>

// Problem constants (B=8, C=128, H=W=48 -> N=2304)
#define NTOK 2304
#define CC   128

typedef __attribute__((ext_vector_type(8))) short bf16x8;
typedef __attribute__((ext_vector_type(4))) float f32x4;

// round-to-nearest-even fp32 -> bf16
__device__ __forceinline__ unsigned f2bf(float f) {
  unsigned int u = __builtin_bit_cast(unsigned int, f);
  u += 0x7FFFu + ((u >> 16) & 1u);
  return (u >> 16) & 0xFFFFu;
}
__device__ __forceinline__ unsigned pk2(float a, float b) {
  return f2bf(a) | (f2bf(b) << 16);
}

// Prep: exact fp32 squared norms. sx from x, sy from y (reference quirk:
// out[b][i][j] = ||x_i||^2 + ||y_j||^2 - 2*y_i.x_j -- row i uses x's norm).
__global__ __launch_bounds__(256) void pwd_prep_norms(
    const float* __restrict__ x, const float* __restrict__ y,
    float* __restrict__ sx, float* __restrict__ sy) {
  __shared__ float part[4][64];
  const int tid = threadIdx.x;
  const int nl = tid & 63;
  const int cq = tid >> 6;
  const int n = blockIdx.x * 64 + nl;
  const int b = blockIdx.y;
  const float* src = blockIdx.z ? y : x;
  const float* p = src + ((size_t)b * CC + cq * 32) * NTOK + n;
  float s = 0.f;
#pragma unroll
  for (int c = 0; c < 32; ++c) {
    float v = p[(size_t)c * NTOK];
    s = fmaf(v, v, s);
  }
  part[cq][nl] = s;
  __syncthreads();
  if (tid < 64) {
    float t = part[0][tid] + part[1][tid] + part[2][tid] + part[3][tid];
    float* dst = blockIdx.z ? sy : sx;
    dst[b * NTOK + blockIdx.x * 64 + tid] = t;
  }
}

// Persistent row-panel GEMM: block owns 128 rows (A = y@i0, staged once) and
// loops over T=4 j-tiles of 64 cols (B = x@j, double-buffered 2x16KB).
// Pipeline per iter: issue B(t+1) loads -> MFMA(t) -> store(t) -> ds_write
// B(t+1) -> barrier. LDS = 64KB exactly -> 2 blocks/CU -> 4 waves/SIMD.
// Slot swizzle slot=(k>>3)^(n&15)^((n>>4)&3), conflict-free write+read.
__global__ __launch_bounds__(512, 4) void pwd_gemm(
    const float* __restrict__ x, const float* __restrict__ y,
    const float* __restrict__ sx, const float* __restrict__ sy,
    float* __restrict__ out) {
  __shared__ __attribute__((aligned(16))) char smem[65536];
  char* const smA  = smem;            // 128 rows * 256 B
  char* const smB0 = smem + 32768;    // 64 rows * 256 B
  char* const smB1 = smem + 49152;

  const int tid = threadIdx.x;

  // XCD swizzle: grid 1296 = 8*162; bid%8 = batch (one batch per XCD's L2).
  const int bid = blockIdx.x;
  const int b   = bid & 7;
  const int rem = bid >> 3;           // 0..161
  const int p   = rem / 9;            // row-panel 0..17
  const int jg  = rem - 9 * p;        // j-group 0..8
  const int i0  = p * 128;
  const int j0  = jg * 256;           // this block's 4 tiles: j0 + t*64

  const int w  = tid >> 6;
  const int l  = tid & 63;
  const int lr = l & 15;
  const int lg = l >> 4;
  const int wm = (w >> 1) * 32;       // wave row band (4 bands x 32)
  const int wn = (w & 1) * 32;        // wave col band (2 bands x 32)

  // ---------------- A stage: y[k][i0+n] -> smA[n][k] bf16 -------------------
  {
    const int g = tid & 31;
    const int q = tid >> 5;           // k-block 0..15 (8 k's)
    const float* base = y + ((size_t)b * CC + q * 8) * NTOK + i0 + 4 * g;
    float v[8][4];
#pragma unroll
    for (int kk = 0; kk < 8; ++kk)
      *(float4*)v[kk] = *(const float4*)(base + (size_t)kk * NTOK);
#pragma unroll
    for (int c = 0; c < 4; ++c) {
      const int n = 4 * g + c;
      uint4 wv;
      wv.x = pk2(v[0][c], v[1][c]);
      wv.y = pk2(v[2][c], v[3][c]);
      wv.z = pk2(v[4][c], v[5][c]);
      wv.w = pk2(v[6][c], v[7][c]);
      const int slot = q ^ (n & 15) ^ ((n >> 4) & 3);
      *(uint4*)(smA + n * 256 + slot * 16) = wv;
    }
  }

  // ---------------- hoist norms into registers ------------------------------
  float sxr[2][4];
#pragma unroll
  for (int mf = 0; mf < 2; ++mf)
#pragma unroll
    for (int r = 0; r < 4; ++r)
      sxr[mf][r] = sx[b * NTOK + i0 + wm + mf * 16 + lg * 4 + r];
  float syr[4][2];
#pragma unroll
  for (int t = 0; t < 4; ++t)
#pragma unroll
    for (int nf = 0; nf < 2; ++nf)
      syr[t][nf] = sy[b * NTOK + j0 + t * 64 + wn + nf * 16 + lr];

  // ---------------- B staging mapping ---------------------------------------
  const int g3 = tid & 15;            // col group (4 cols)
  const int qb = tid >> 4;            // k-quad 0..31 (4 k's)
  const float* const xbase = x + ((size_t)b * CC + qb * 4) * NTOK + j0 + 4 * g3;

  float pref[4][4];                   // [k][col]
#pragma unroll
  for (int kk = 0; kk < 4; ++kk)
    *(float4*)pref[kk] = *(const float4*)(xbase + (size_t)kk * NTOK);
#pragma unroll
  for (int c = 0; c < 4; ++c) {       // write B(0) -> smB0
    const int n = 4 * g3 + c;
    uint2 w2;
    w2.x = pk2(pref[0][c], pref[1][c]);
    w2.y = pk2(pref[2][c], pref[3][c]);
    const int slot = (qb >> 1) ^ (n & 15) ^ ((n >> 4) & 3);
    *(uint2*)(smB0 + n * 256 + slot * 16 + (qb & 1) * 8) = w2;
  }
  __syncthreads();

#pragma unroll
  for (int t = 0; t < 4; ++t) {
    char* const cur = (t & 1) ? smB1 : smB0;
    char* const nxt = (t & 1) ? smB0 : smB1;

    // issue B(t+1) global loads early (latency hides under MFMA+stores)
    if (t < 3) {
#pragma unroll
      for (int kk = 0; kk < 4; ++kk)
        *(float4*)pref[kk] =
            *(const float4*)(xbase + (size_t)kk * NTOK + (t + 1) * 64);
    }

    // ---------------- MFMA: wave tile 32x32 ---------------------------------
    f32x4 acc[2][2] = {};
#pragma unroll
    for (int ks = 0; ks < 4; ++ks) {
      const int o = ks * 4 + lg;
      bf16x8 af[2], bfv[2];
#pragma unroll
      for (int mf = 0; mf < 2; ++mf) {
        const int n = wm + mf * 16 + lr;
        const int slot = o ^ (n & 15) ^ ((n >> 4) & 3);
        af[mf] = *(const bf16x8*)(smA + n * 256 + slot * 16);
      }
#pragma unroll
      for (int nf = 0; nf < 2; ++nf) {
        const int n = wn + nf * 16 + lr;
        const int slot = o ^ (n & 15) ^ ((n >> 4) & 3);
        bfv[nf] = *(const bf16x8*)(cur + n * 256 + slot * 16);
      }
#pragma unroll
      for (int mf = 0; mf < 2; ++mf)
#pragma unroll
        for (int nf = 0; nf < 2; ++nf)
          acc[mf][nf] = __builtin_amdgcn_mfma_f32_16x16x32_bf16(
              af[mf], bfv[nf], acc[mf][nf], 0, 0, 0);
    }

    // ---------------- epilogue: nontemporal stores --------------------------
#pragma unroll
    for (int mf = 0; mf < 2; ++mf)
#pragma unroll
      for (int nf = 0; nf < 2; ++nf)
#pragma unroll
        for (int r = 0; r < 4; ++r) {
          const int row = wm + mf * 16 + lg * 4 + r;   // C/D layout (m89)
          const int col = wn + nf * 16 + lr;
          const float vv = sxr[mf][r] + syr[t][nf] - 2.0f * acc[mf][nf][r];
          __builtin_nontemporal_store(
              vv,
              out + ((size_t)b * NTOK + (i0 + row)) * NTOK + j0 + t * 64 + col);
        }

    // ---------------- stage B(t+1) into the other buffer --------------------
    if (t < 3) {
#pragma unroll
      for (int c = 0; c < 4; ++c) {
        const int n = 4 * g3 + c;
        uint2 w2;
        w2.x = pk2(pref[0][c], pref[1][c]);
        w2.y = pk2(pref[2][c], pref[3][c]);
        const int slot = (qb >> 1) ^ (n & 15) ^ ((n >> 4) & 3);
        *(uint2*)(nxt + n * 256 + slot * 16 + (qb & 1) * 8) = w2;
      }
      __syncthreads();
    }
  }
}

extern "C" void kernel_launch(void* const* d_in, const int* in_sizes, int n_in,
                              void* d_out, int out_size, void* d_ws, size_t ws_size,
                              hipStream_t stream) {
  (void)in_sizes; (void)n_in; (void)out_size; (void)ws_size;
  const float* x = (const float*)d_in[0];
  const float* y = (const float*)d_in[1];
  float* out = (float*)d_out;
  float* sx = (float*)d_ws;              // 8*2304 fp32
  float* sy = sx + 8 * NTOK;             // 8*2304 fp32 (total 147,456 B of ws)

  dim3 gp(NTOK / 64, 8, 2);
  pwd_prep_norms<<<gp, dim3(256), 0, stream>>>(x, y, sx, sy);

  dim3 gg(8 * 18 * 9);                   // 1296 blocks: batch x panel x j-group
  pwd_gemm<<<gg, dim3(512), 0, stream>>>(x, y, sx, sy, out);
}

// Round 7
// 55.474 us; speedup vs baseline: 1.1362x; 1.1362x over previous
//
#include <hip/hip_runtime.h>

// Problem constants (B=8, C=128, H=W=48 -> N=2304)
#define NTOK 2304
#define CC   128

typedef __attribute__((ext_vector_type(8))) short bf16x8;
typedef __attribute__((ext_vector_type(4))) float f32x4;

// round-to-nearest-even fp32 -> bf16
__device__ __forceinline__ unsigned f2bf(float f) {
  unsigned int u = __builtin_bit_cast(unsigned int, f);
  u += 0x7FFFu + ((u >> 16) & 1u);
  return (u >> 16) & 0xFFFFu;
}
__device__ __forceinline__ unsigned pk2(float a, float b) {
  return f2bf(a) | (f2bf(b) << 16);
}

// Prep: exact fp32 squared norms. sx from x, sy from y (reference quirk:
// out[b][i][j] = ||x_i||^2 + ||y_j||^2 - 2*y_i.x_j -- row i uses x's norm).
__global__ __launch_bounds__(256) void pwd_prep_norms(
    const float* __restrict__ x, const float* __restrict__ y,
    float* __restrict__ sx, float* __restrict__ sy) {
  __shared__ float part[4][64];
  const int tid = threadIdx.x;
  const int nl = tid & 63;
  const int cq = tid >> 6;
  const int n = blockIdx.x * 64 + nl;
  const int b = blockIdx.y;
  const float* src = blockIdx.z ? y : x;
  const float* p = src + ((size_t)b * CC + cq * 32) * NTOK + n;
  float s = 0.f;
#pragma unroll
  for (int c = 0; c < 32; ++c) {
    float v = p[(size_t)c * NTOK];
    s = fmaf(v, v, s);
  }
  part[cq][nl] = s;
  __syncthreads();
  if (tid < 64) {
    float t = part[0][tid] + part[1][tid] + part[2][tid] + part[3][tid];
    float* dst = blockIdx.z ? sy : sx;
    dst[b * NTOK + blockIdx.x * 64 + tid] = t;
  }
}

// Main GEMM, operand-SWAPPED so stores are dwordx4 along j:
//   D[m=j][n=i] = sum_k x[k][j] * y[k][i]  (= y_i . x_j)
// A-operand = x panel @ j0, B-operand = y panel @ i0, both staged bf16
// K-contiguous in LDS, slot swizzle slot=(k>>3)^(n&15)^((n>>4)&3)
// (conflict-free for ds_write_b128 and ds_read_b128).
// C/D 16x16 layout: n(=i)=lane&15, m(=j)=(lane>>4)*4+reg -> each lane's acc
// quad is 4 CONSECUTIVE j -> direct float4 store to out[b][i][j..j+3].
// 512 threads, 8 waves (2 j-bands x 4 i-bands, wave tile 64j x 32i),
// LDS 64KB -> 2 blocks/CU -> 4 waves/SIMD.
__global__ __launch_bounds__(512, 4) void pwd_gemm(
    const float* __restrict__ x, const float* __restrict__ y,
    const float* __restrict__ sx, const float* __restrict__ sy,
    float* __restrict__ out) {
  __shared__ __attribute__((aligned(16))) char smem[65536];
  char* const smX = smem;            // x panel: 128 j-rows * 256 B
  char* const smY = smem + 32768;    // y panel: 128 i-rows * 256 B

  const int tid = threadIdx.x;

  // XCD swizzle: grid 2592 = 8*324; bid%8 = batch (one batch per XCD's L2).
  const int bid = blockIdx.x;
  const int b   = bid & 7;
  const int rem = bid >> 3;            // 0..323
  const int byy = rem / 18;
  const int bxx = rem - byy * 18;
  const int i0 = byy * 128;            // output rows (i)
  const int j0 = bxx * 128;            // output cols (j)

  const int g  = tid & 31;             // column group: 4 tokens
  const int q  = tid >> 5;             // k-block 0..15 -> k in [8q, 8q+8)
  const int k0 = q * 8;
  const int w  = tid >> 6;             // wave 0..7
  const int l  = tid & 63;
  const int lr = l & 15;
  const int lg = l >> 4;
  const int wj = (w >> 2) * 64;        // wave j band (2 bands x 64)
  const int wi = (w & 3) * 32;         // wave i band (4 bands x 32)

  // ---------------- stage x -> smX (rows = local j) -------------------------
  {
    const float* base = x + ((size_t)b * CC + k0) * NTOK + j0 + 4 * g;
    float v[8][4];
#pragma unroll
    for (int kk = 0; kk < 8; ++kk)
      *(float4*)v[kk] = *(const float4*)(base + (size_t)kk * NTOK);
#pragma unroll
    for (int c = 0; c < 4; ++c) {
      const int n = 4 * g + c;
      uint4 wv;
      wv.x = pk2(v[0][c], v[1][c]);
      wv.y = pk2(v[2][c], v[3][c]);
      wv.z = pk2(v[4][c], v[5][c]);
      wv.w = pk2(v[6][c], v[7][c]);
      const int slot = q ^ (n & 15) ^ ((n >> 4) & 3);
      *(uint4*)(smX + n * 256 + slot * 16) = wv;
    }
  }
  // ---------------- stage y -> smY (rows = local i) -------------------------
  {
    const float* base = y + ((size_t)b * CC + k0) * NTOK + i0 + 4 * g;
    float v[8][4];
#pragma unroll
    for (int kk = 0; kk < 8; ++kk)
      *(float4*)v[kk] = *(const float4*)(base + (size_t)kk * NTOK);
#pragma unroll
    for (int c = 0; c < 4; ++c) {
      const int n = 4 * g + c;
      uint4 wv;
      wv.x = pk2(v[0][c], v[1][c]);
      wv.y = pk2(v[2][c], v[3][c]);
      wv.z = pk2(v[4][c], v[5][c]);
      wv.w = pk2(v[6][c], v[7][c]);
      const int slot = q ^ (n & 15) ^ ((n >> 4) & 3);
      *(uint4*)(smY + n * 256 + slot * 16) = wv;
    }
  }

  // ---------------- hoist norms into registers (overlap with barrier) -------
  // row term: sx (x norms) at i = i0+wi+nf*16+lr  -> scalar per nf
  // col term: sy (y norms) at j quad = j0+wj+mf*16+lg*4 -> float4 per mf
  float sxr[2];
#pragma unroll
  for (int nf = 0; nf < 2; ++nf)
    sxr[nf] = sx[b * NTOK + i0 + wi + nf * 16 + lr];
  f32x4 syq[4];
#pragma unroll
  for (int mf = 0; mf < 4; ++mf)
    syq[mf] = *(const f32x4*)(sy + b * NTOK + j0 + wj + mf * 16 + lg * 4);

  __syncthreads();

  // ---------------- compute: wave tile 64j x 32i ----------------------------
  f32x4 acc[4][2] = {};
#pragma unroll
  for (int ks = 0; ks < 4; ++ks) {
    const int o = ks * 4 + lg;           // 16B slot (8 k's)
    bf16x8 ax[4], by[2];
#pragma unroll
    for (int mf = 0; mf < 4; ++mf) {     // A-frag rows = j
      const int n = wj + mf * 16 + lr;
      const int slot = o ^ (n & 15) ^ ((n >> 4) & 3);
      ax[mf] = *(const bf16x8*)(smX + n * 256 + slot * 16);
    }
#pragma unroll
    for (int nf = 0; nf < 2; ++nf) {     // B-frag rows = i
      const int n = wi + nf * 16 + lr;
      const int slot = o ^ (n & 15) ^ ((n >> 4) & 3);
      by[nf] = *(const bf16x8*)(smY + n * 256 + slot * 16);
    }
#pragma unroll
    for (int mf = 0; mf < 4; ++mf)
#pragma unroll
      for (int nf = 0; nf < 2; ++nf)
        acc[mf][nf] = __builtin_amdgcn_mfma_f32_16x16x32_bf16(
            ax[mf], by[nf], acc[mf][nf], 0, 0, 0);
  }

  // ---------------- epilogue: float4 nontemporal stores along j -------------
#pragma unroll
  for (int nf = 0; nf < 2; ++nf) {
    const int i = i0 + wi + nf * 16 + lr;
    float* const rowp = out + ((size_t)b * NTOK + i) * NTOK;
#pragma unroll
    for (int mf = 0; mf < 4; ++mf) {
      const int jb = j0 + wj + mf * 16 + lg * 4;
      f32x4 vv;
#pragma unroll
      for (int r = 0; r < 4; ++r)
        vv[r] = sxr[nf] + syq[mf][r] - 2.0f * acc[mf][nf][r];
      __builtin_nontemporal_store(vv, (f32x4*)(rowp + jb));
    }
  }
}

extern "C" void kernel_launch(void* const* d_in, const int* in_sizes, int n_in,
                              void* d_out, int out_size, void* d_ws, size_t ws_size,
                              hipStream_t stream) {
  (void)in_sizes; (void)n_in; (void)out_size; (void)ws_size;
  const float* x = (const float*)d_in[0];
  const float* y = (const float*)d_in[1];
  float* out = (float*)d_out;
  float* sx = (float*)d_ws;              // 8*2304 fp32
  float* sy = sx + 8 * NTOK;             // 8*2304 fp32 (total 147,456 B of ws)

  dim3 gp(NTOK / 64, 8, 2);
  pwd_prep_norms<<<gp, dim3(256), 0, stream>>>(x, y, sx, sy);

  dim3 gg(18 * 18 * 8);                  // one 128x128 tile per block
  pwd_gemm<<<gg, dim3(512), 0, stream>>>(x, y, sx, sy, out);
}